// Round 5
// baseline (10.081 us; speedup 1.0000x reference)
//
#include <hip/hip_runtime.h>

#define NT    2048
#define D     16
#define NSEG  32
#define NOUTC 136

typedef __attribute__((ext_vector_type(8))) short bf16x8;
typedef __attribute__((ext_vector_type(4))) float f32x4;

__global__ __launch_bounds__(256) void logsig_kernel(
    const float* __restrict__ inp,     // [B, NT, D]
    const int*   __restrict__ length,  // [G]
    float*       __restrict__ out,     // [B, NSEG, NOUTC]
    int batch_size)
{
    const int blk  = blockIdx.x;       // 0..1023
    const int b    = blk >> 3;
    const int sq   = blk & 7;
    const int tid  = threadIdx.x;
    const int wave = tid >> 6;         // 4 fully-independent waves, one segment each
    const int lane = tid & 63;
    const int s    = sq * 4 + wave;
    const int g    = b / batch_size;

    // segment boundaries: tv = round(1 + (L-1)*k/32) - 1, bit-match numpy RNE
    const float Lm1 = __fadd_rn((float)length[g], -1.0f);
    const int t0 = (int)rintf(__fadd_rn(1.0f, __fmul_rn(Lm1, (float)s       * (1.0f/32.0f)))) - 1;
    const int t1 = (int)rintf(__fadd_rn(1.0f, __fmul_rn(Lm1, (float)(s + 1) * (1.0f/32.0f)))) - 1;
    const int n  = t1 - t0;            // steps, ~7..64

    const float* xrow = inp + (size_t)b * (NT * D);

    const int ch = lane & 15;          // this lane's A-row / B-col channel (j)
    const int tb = lane >> 4;          // k-block within chunk

    // --- both orientations in-register:
    //     accM(i,j) = sum_k x_i dx_j ;  accN(i,j) = sum_k dx_i x_j = M(j,i)
    f32x4 accM = {0.f, 0.f, 0.f, 0.f};
    f32x4 accN = {0.f, 0.f, 0.f, 0.f};
    const int nch = (n > 32) ? 2 : 1;  // wave-uniform
    for (int c = 0; c < nch; ++c) {
        const int kb = c * 32 + 8 * tb;
        float xv[9];
        #pragma unroll
        for (int e = 0; e < 9; ++e) {
            int t = t0 + kb + e;                 // clamp: masked lanes must not fault
            t = (t < NT - 1) ? t : (NT - 1);
            xv[e] = xrow[t * D + ch];            // wave-coalesced: 4 x 64B rows per e
        }
        bf16x8 Ah, Al, Bh, Bl;
        #pragma unroll
        for (int e = 0; e < 8; ++e) {
            const int idx = kb + e;
            const float xm  = (idx <= n) ? xv[e] : 0.0f;
            const float dxm = (idx <  n) ? (xv[e + 1] - xv[e]) : 0.0f;
            const unsigned bx = __float_as_uint(xm);
            Ah[e] = (short)(bx >> 16);                               // bf16 hi (truncate)
            const float lx = xm - __uint_as_float(bx & 0xFFFF0000u); // exact remainder
            Al[e] = (short)(__float_as_uint(lx) >> 16);
            const unsigned bd = __float_as_uint(dxm);
            Bh[e] = (short)(bd >> 16);
            const float ld = dxm - __uint_as_float(bd & 0xFFFF0000u);
            Bl[e] = (short)(__float_as_uint(ld) >> 16);
        }
        accM = __builtin_amdgcn_mfma_f32_16x16x32_bf16(Ah, Bh, accM, 0, 0, 0);
        accM = __builtin_amdgcn_mfma_f32_16x16x32_bf16(Ah, Bl, accM, 0, 0, 0);
        accM = __builtin_amdgcn_mfma_f32_16x16x32_bf16(Al, Bh, accM, 0, 0, 0);
        accN = __builtin_amdgcn_mfma_f32_16x16x32_bf16(Bh, Ah, accN, 0, 0, 0);
        accN = __builtin_amdgcn_mfma_f32_16x16x32_bf16(Bh, Al, accN, 0, 0, 0);
        accN = __builtin_amdgcn_mfma_f32_16x16x32_bf16(Bl, Ah, accN, 0, 0, 0);
    }

    // --- epilogue, all in-register: lane holds rows i = 4*tb+e, col j = ch ---
    const size_t obase = ((size_t)b * NSEG + s) * NOUTC;
    const int j = ch;
    const float xa_j = xrow[t0 * D + j];
    const float xe_j = xrow[t1 * D + j];
    const float l1j  = xe_j - xa_j;

    if (tb == 0) {
        out[obase + j] = l1j;                                // lvl1
    }
    #pragma unroll
    for (int e = 0; e < 4; ++e) {
        const int i = 4 * tb + e;
        if (i < j) {
            const float xa_i = xrow[t0 * D + i];             // L1-hit (same lines as above)
            const float xe_i = xrow[t1 * D + i];
            const float corr = xa_i * l1j - xa_j * (xe_i - xa_i);
            const int oidx   = 15 * i - (i * (i - 1)) / 2 + (j - i - 1);
            out[obase + D + oidx] = 0.5f * (accM[e] - accN[e] - corr);  // lvl2
        }
    }
}

extern "C" void kernel_launch(void* const* d_in, const int* in_sizes, int n_in,
                              void* d_out, int out_size, void* d_ws, size_t ws_size,
                              hipStream_t stream)
{
    const float* inp    = (const float*)d_in[0];
    const int*   length = (const int*)d_in[1];
    float*       out    = (float*)d_out;

    const int B  = in_sizes[0] / (NT * D);   // 128
    const int G  = in_sizes[1];              // 8
    const int bs = B / G;                    // 16

    const int grid = B * (NSEG / 4);         // 1024 blocks x 4 independent waves
    logsig_kernel<<<grid, 256, 0, stream>>>(inp, length, out, bs);
}

// Round 6
// 9.866 us; speedup vs baseline: 1.0218x; 1.0218x over previous
//
#include <hip/hip_runtime.h>

#define NT    2048
#define D     16
#define NSEG  32
#define NOUTC 136

typedef __attribute__((ext_vector_type(8))) short bf16x8;
typedef __attribute__((ext_vector_type(4))) float f32x4;

__global__ __launch_bounds__(256) void logsig_kernel(
    const float* __restrict__ inp,     // [B, NT, D]
    const int*   __restrict__ length,  // [G]
    float*       __restrict__ out,     // [B, NSEG, NOUTC]
    int batch_size)
{
    const int blk  = blockIdx.x;       // 0..1023
    const int b    = blk >> 3;
    const int sq   = blk & 7;
    const int tid  = threadIdx.x;
    const int wave = tid >> 6;         // 4 fully-independent waves, one segment each
    const int lane = tid & 63;
    const int s    = sq * 4 + wave;
    const int g    = b / batch_size;

    // segment boundaries: tv = round(1 + (L-1)*k/32) - 1, bit-match numpy RNE
    const float Lm1 = __fadd_rn((float)length[g], -1.0f);
    const int t0 = (int)rintf(__fadd_rn(1.0f, __fmul_rn(Lm1, (float)s       * (1.0f/32.0f)))) - 1;
    const int t1 = (int)rintf(__fadd_rn(1.0f, __fmul_rn(Lm1, (float)(s + 1) * (1.0f/32.0f)))) - 1;
    const int n  = t1 - t0;            // steps, ~8..64

    const float* xrow = inp + (size_t)b * (NT * D);

    const int ch = lane & 15;          // this lane's channel
    const int tb = lane >> 4;          // k-block within chunk

    // Telescoped cross-area: M - N = sum_k x_i(k)x_j(k+1) - x_i(k+1)x_j(k)
    //                              = accP - accT.
    // Clamping t to t1 makes all k >= n terms x(t1)*x(t1) on both sides -> exact
    // cancellation, so NO masking is needed anywhere.
    f32x4 accP = {0.f, 0.f, 0.f, 0.f};
    f32x4 accT = {0.f, 0.f, 0.f, 0.f};
    const int nch = (n > 32) ? 2 : 1;  // wave-uniform
    for (int c = 0; c < nch; ++c) {
        const int kb = c * 32 + 8 * tb;
        short xh[9], xl[9];
        #pragma unroll
        for (int e = 0; e < 9; ++e) {
            int t = t0 + kb + e;
            t = (t < t1) ? t : t1;               // clamp to segment end
            const float xv = xrow[t * D + ch];   // wave-coalesced 4 x 64B rows
            const unsigned bx = __float_as_uint(xv);
            xh[e] = (short)(bx >> 16);                                // bf16 hi (truncate)
            const float lx = xv - __uint_as_float(bx & 0xFFFF0000u);  // exact remainder
            xl[e] = (short)(__float_as_uint(lx) >> 16);               // bf16 lo
        }
        bf16x8 Ah, Al, Ph, Pl;
        #pragma unroll
        for (int e = 0; e < 8; ++e) {
            Ah[e] = xh[e];     Al[e] = xl[e];      // A = x[k]
            Ph[e] = xh[e + 1]; Pl[e] = xl[e + 1];  // P = x[k+1]
        }
        accP = __builtin_amdgcn_mfma_f32_16x16x32_bf16(Ah, Ph, accP, 0, 0, 0);
        accP = __builtin_amdgcn_mfma_f32_16x16x32_bf16(Ah, Pl, accP, 0, 0, 0);
        accP = __builtin_amdgcn_mfma_f32_16x16x32_bf16(Al, Ph, accP, 0, 0, 0);
        accT = __builtin_amdgcn_mfma_f32_16x16x32_bf16(Ph, Ah, accT, 0, 0, 0);
        accT = __builtin_amdgcn_mfma_f32_16x16x32_bf16(Ph, Al, accT, 0, 0, 0);
        accT = __builtin_amdgcn_mfma_f32_16x16x32_bf16(Pl, Ah, accT, 0, 0, 0);
    }

    // --- epilogue, all in-register: lane holds rows i = 4*tb+e, col j = ch ---
    const size_t obase = ((size_t)b * NSEG + s) * NOUTC;
    const int j = ch;
    const float xa_j = xrow[t0 * D + j];
    const float xe_j = xrow[t1 * D + j];
    const float l1j  = xe_j - xa_j;

    if (tb == 0) {
        out[obase + j] = l1j;                                // lvl1
    }
    #pragma unroll
    for (int e = 0; e < 4; ++e) {
        const int i = 4 * tb + e;
        if (i < j) {
            const float xa_i = xrow[t0 * D + i];             // L1-hit
            const float xe_i = xrow[t1 * D + i];
            const float corr = xa_i * l1j - xa_j * (xe_i - xa_i);
            const int oidx   = 15 * i - (i * (i - 1)) / 2 + (j - i - 1);
            out[obase + D + oidx] = 0.5f * (accP[e] - accT[e] - corr);  // lvl2
        }
    }
}

extern "C" void kernel_launch(void* const* d_in, const int* in_sizes, int n_in,
                              void* d_out, int out_size, void* d_ws, size_t ws_size,
                              hipStream_t stream)
{
    const float* inp    = (const float*)d_in[0];
    const int*   length = (const int*)d_in[1];
    float*       out    = (float*)d_out;

    const int B  = in_sizes[0] / (NT * D);   // 128
    const int G  = in_sizes[1];              // 8
    const int bs = B / G;                    // 16

    const int grid = B * (NSEG / 4);         // 1024 blocks x 4 independent waves
    logsig_kernel<<<grid, 256, 0, stream>>>(inp, length, out, bs);
}